// Round 3
// baseline (78.534 us; speedup 1.0000x reference)
//
#include <hip/hip_runtime.h>
#include <hip/hip_fp16.h>

#define MODV 26
#define HALFV 13
#define NV 64
#define BV 1024
#define ESTRIDE 832   // uints per ws entry = 3328 B, unpadded (was 4096)

typedef float v2f __attribute__((ext_vector_type(2)));
typedef _Float16 h2 __attribute__((ext_vector_type(2)));

// ---------------------------------------------------------------------------
// Spectral representation (R4/R5). For each (l,p,i):
//   Kp[c] = sum_{k: p*k%26==c} softmax(key_param[l,i,:])[k]
// CRT split (Z26 = Z2 x Z13): S[r] = Kp[even]+Kp[odd], D[r] = Kp[even]-Kp[odd]
// 13-pt DFT: X_j = sum_r x[r] e^{-2pi i jr/13}, j=0..6 (X_0 real).
// Chain = 63 pointwise complex products + ONE inverse DFT at the end.
// Entry = 13 packed-fp16 words: w[0..6]=(S_re,D_re) j=0..6, w[7..12]=(S_im,D_im).
//
// R6: word-group-major entry layout -> every VMEM instruction coalesced.
// R7: (a) entry stride 4096->3328 B (ws 6.8->5.5 MB, better L2/XCD fit);
//     (b) chain main loop: manual depth-2 prefetch ping-pong (named regs,
//         statically unrolled -> no scratch);
//     (c) epilogue parallelized 4x: final spectrum -> LDS, thread (row,q)
//         computes r in {q,q+4,q+8(,12)}; normalizer needs no reduction
//         because sum_r V[r].x == 13 * X0 (DC) exactly.
// R8: identical resubmit of R7 (previous round was a container infra
//     failure, not a kernel failure).
// Per (l,p) entry (uint offsets): [0,256) uint4 {w0..w3} lane i at i*4;
// [256,512) {w4..w7}; [512,768) {w8..w11}; [768,832) w12.
// ---------------------------------------------------------------------------

__device__ __forceinline__ h2 bch2(uint u) { return __builtin_bit_cast(h2, u); }
__device__ __forceinline__ uint bcu(h2 v) { return __builtin_bit_cast(uint, v); }

__device__ __forceinline__ uint packw(v2f v)
{
    uint hs = (uint)__half_as_ushort(__float2half_rn(v.x));
    uint hd = (uint)__half_as_ushort(__float2half_rn(v.y));
    return hs | (hd << 16);
}

// state (RE[0..6], IM[1..6]) *= spectrum in packed words w13[0..12]
__device__ __forceinline__ void mulspec_w(h2* __restrict__ RE,
                                          h2* __restrict__ IM,
                                          const uint* __restrict__ w13)
{
    RE[0] *= bch2(w13[0]);
#pragma unroll
    for (int j = 1; j < 7; j++) {
        h2 kr = bch2(w13[j]), ki = bch2(w13[6 + j]);
        h2 nre = RE[j] * kr - IM[j] * ki;
        h2 nim = RE[j] * ki + IM[j] * kr;
        RE[j] = nre; IM[j] = nim;
    }
}

// ---------------------------------------------------------------------------
// Kernel 1: grid (64 l-slabs x 7 p-groups) x 256. Wave w handles
// p = 4*blockIdx.y + w (skip p>=26); one statically-unrolled p-block per
// wave (wave-uniform branch -> compile-time scatter indices).
// ---------------------------------------------------------------------------
__global__ __launch_bounds__(256)
void prep_kernel(const float* __restrict__ key_param,
                 float* __restrict__ key_probs_out,
                 uint* __restrict__ ws)
{
    __shared__ float slab[NV * MODV];   // 6656 B
    int l = blockIdx.x;
    int t = threadIdx.x;
    int i = t & 63;
    int w = t >> 6;
    int p = (blockIdx.y << 2) + w;

#pragma unroll
    for (int j = 0; j < 7; j++) {
        int idx = t + j * 256;
        if (idx < NV * MODV) slab[idx] = key_param[l * NV * MODV + idx];
    }
    __syncthreads();

    float x[MODV];
    float m = -1e30f;
#pragma unroll
    for (int k = 0; k < MODV; k++) {
        x[k] = slab[i * MODV + k];
        m = fmaxf(m, x[k]);
    }
    float s = 0.f;
#pragma unroll
    for (int k = 0; k < MODV; k++) { x[k] = __expf(x[k] - m); s += x[k]; }
    float inv = 1.f / s;
#pragma unroll
    for (int k = 0; k < MODV; k++) x[k] *= inv;

    if (blockIdx.y == 0 && w == 0) {
#pragma unroll
        for (int k = 0; k < MODV; k++)
            key_probs_out[((l << 6) + i) * MODV + k] = x[k];
    }
    if (p >= MODV) return;

    float c13[HALFV], s13[HALFV];
#pragma unroll
    for (int k = 0; k < HALFV; k++) {
        float a = 0.4833219467f * (float)k;    // 2*pi/13
        __sincosf(a, &s13[k], &c13[k]);
    }

#pragma unroll
    for (int pc = 0; pc < MODV; pc++) {
        if (pc != p) continue;          // wave-uniform; one block executes

        float Kp[MODV];
#pragma unroll
        for (int c = 0; c < MODV; c++) Kp[c] = 0.f;
#pragma unroll
        for (int k = 0; k < MODV; k++) Kp[(pc * k) % MODV] += x[k];  // static

        v2f V[HALFV];                    // (S[r], D[r])
#pragma unroll
        for (int r = 0; r < HALFV; r++) {
            int c0 = (14 * r) % MODV;
            int c1 = (13 + 14 * r) % MODV;
            v2f v; v.x = Kp[c0] + Kp[c1]; v.y = Kp[c0] - Kp[c1];
            V[r] = v;
        }

        uint hw[HALFV];
        {   // j = 0 (DC, real)
            v2f acc = V[0];
#pragma unroll
            for (int r = 1; r < HALFV; r++) acc += V[r];
            hw[0] = packw(acc);
        }
#pragma unroll
        for (int j = 1; j < 7; j++) {
            v2f re = V[0];
            v2f im; im.x = 0.f; im.y = 0.f;
#pragma unroll
            for (int r = 1; r < HALFV; r++) {
                int a = (j * r) % HALFV;            // compile-time
                re += V[r] * c13[a];
                im -= V[r] * s13[a];
            }
            hw[j]     = packw(re);
            hw[6 + j] = packw(im);
        }
        // unpadded transposed entry: all four stores unit-stride coalesced
        uint* dst = ws + (size_t)(l * MODV + pc) * ESTRIDE;
        *(uint4*)(dst + (i << 2))         = make_uint4(hw[0], hw[1], hw[2],  hw[3]);
        *(uint4*)(dst + 256 + (i << 2))   = make_uint4(hw[4], hw[5], hw[6],  hw[7]);
        *(uint4*)(dst + 512 + (i << 2))   = make_uint4(hw[8], hw[9], hw[10], hw[11]);
        dst[768 + i] = hw[12];
    }
}

// ---------------------------------------------------------------------------
// Kernel 2: one block (4 waves) per b. Wave w pointwise-multiplies the 16
// spectra for l in [16w,16w+16) in packed fp16 (depth-2 prefetch), LDS tree
// combine, then the fp32 inverse DFT + log epilogue is parallelized over all
// 256 threads (4 threads per row), and the 64x26 block is stored coalesced.
// ---------------------------------------------------------------------------
__global__ __launch_bounds__(256, 4)
void chain_kernel(const int* __restrict__ P,
                  const uint* __restrict__ ws,
                  float* __restrict__ out)
{
    __shared__ int Pl[NV];
    __shared__ uint sbuf[2][64][HALFV];  // 6656 B
    __shared__ float obuf[NV * MODV];    // 6656 B, epilogue staging
    __shared__ float c2tab[HALFV], s2tab[HALFV];  // 2*cos, 2*sin tables

    int b = blockIdx.x;
    int w = threadIdx.x >> 6;
    int i = threadIdx.x & 63;
    if (threadIdx.x < NV) Pl[threadIdx.x] = P[(b << 6) + threadIdx.x];
    if (threadIdx.x < HALFV) {
        float a = 0.4833219467f * (float)threadIdx.x;   // 2*pi/13
        float sv, cv;
        __sincosf(a, &sv, &cv);
        c2tab[threadIdx.x] = 2.f * cv;
        s2tab[threadIdx.x] = 2.f * sv;
    }
    __syncthreads();

    int base = w << 4;
    int i4 = i << 2;                     // uint offset of lane's uint4

#define LOADE(v0, v1, v2, v12, l_)                                        \
    {                                                                     \
        const uint* e_ = ws + (size_t)((l_) * MODV + Pl[l_]) * ESTRIDE;   \
        v0  = *(const uint4*)(e_ + i4);                                   \
        v1  = *(const uint4*)(e_ + 256 + i4);                             \
        v2  = *(const uint4*)(e_ + 512 + i4);                             \
        v12 = e_[768 + i];                                                \
    }

    h2 RE[7], IM[7];                     // IM[0] unused
    {
        uint4 a, bq, cq; uint w12;
        LOADE(a, bq, cq, w12, base);
        uint wd[HALFV] = {a.x, a.y, a.z, a.w, bq.x, bq.y, bq.z, bq.w,
                          cq.x, cq.y, cq.z, cq.w, w12};
#pragma unroll
        for (int j = 0; j < 7; j++) RE[j] = bch2(wd[j]);
#pragma unroll
        for (int j = 1; j < 7; j++) IM[j] = bch2(wd[6 + j]);
    }

    // depth-2 prefetch ping-pong: A serves odd offsets, B even.
    uint4 A0, A1, A2, B0, B1, B2; uint A12, B12;
    LOADE(A0, A1, A2, A12, base + 1);
    LOADE(B0, B1, B2, B12, base + 2);

#pragma unroll 1
    for (int s = 1; s <= 13; s += 2) {
        {
            uint cw[HALFV] = {A0.x, A0.y, A0.z, A0.w, A1.x, A1.y, A1.z, A1.w,
                              A2.x, A2.y, A2.z, A2.w, A12};
            LOADE(A0, A1, A2, A12, base + s + 2);   // s+2 <= 15 always
            mulspec_w(RE, IM, cw);
        }
        {
            uint cw[HALFV] = {B0.x, B0.y, B0.z, B0.w, B1.x, B1.y, B1.z, B1.w,
                              B2.x, B2.y, B2.z, B2.w, B12};
            if (s + 3 <= 15) LOADE(B0, B1, B2, B12, base + s + 3);
            mulspec_w(RE, IM, cw);
        }
    }
    {   // tail: l = base + 15 (held in A)
        uint cw[HALFV] = {A0.x, A0.y, A0.z, A0.w, A1.x, A1.y, A1.z, A1.w,
                          A2.x, A2.y, A2.z, A2.w, A12};
        mulspec_w(RE, IM, cw);
    }
#undef LOADE

    // tree combine: (w0 <- w1), (w2 <- w3), then w0 <- w2 (packed words)
    if (w == 1 || w == 3) {
        int buf = w >> 1;
#pragma unroll
        for (int j = 0; j < 7; j++) sbuf[buf][i][j] = bcu(RE[j]);
#pragma unroll
        for (int j = 1; j < 7; j++) sbuf[buf][i][6 + j] = bcu(IM[j]);
    }
    __syncthreads();
    if (w == 0) {
        uint K[HALFV];
#pragma unroll
        for (int r = 0; r < HALFV; r++) K[r] = sbuf[0][i][r];
        mulspec_w(RE, IM, K);
    } else if (w == 2) {
        uint K[HALFV];
#pragma unroll
        for (int r = 0; r < HALFV; r++) K[r] = sbuf[1][i][r];
        mulspec_w(RE, IM, K);
#pragma unroll
        for (int j = 0; j < 7; j++) sbuf[1][i][j] = bcu(RE[j]);
#pragma unroll
        for (int j = 1; j < 7; j++) sbuf[1][i][6 + j] = bcu(IM[j]);
    }
    __syncthreads();
    if (w == 0) {
        uint K[HALFV];
#pragma unroll
        for (int r = 0; r < HALFV; r++) K[r] = sbuf[1][i][r];
        mulspec_w(RE, IM, K);
        // publish final spectrum for the parallel epilogue
#pragma unroll
        for (int j = 0; j < 7; j++) sbuf[0][i][j] = bcu(RE[j]);
#pragma unroll
        for (int j = 1; j < 7; j++) sbuf[0][i][6 + j] = bcu(IM[j]);
    }
    __syncthreads();

    // ---- parallel fp32 epilogue: 4 threads per row, r in {q,q+4,q+8(,12)}
    {
        int ir = threadIdx.x >> 2;      // row 0..63
        int q  = threadIdx.x & 3;

        uint wrow[HALFV];
#pragma unroll
        for (int j = 0; j < HALFV; j++) wrow[j] = sbuf[0][ir][j];

        v2f fR[7], fI[7];
#pragma unroll
        for (int j = 0; j < 7; j++) {
            h2 h = bch2(wrow[j]);
            v2f v; v.x = (float)h.x; v.y = (float)h.y; fR[j] = v;
        }
#pragma unroll
        for (int j = 1; j < 7; j++) {
            h2 h = bch2(wrow[6 + j]);
            v2f v; v.x = (float)h.x; v.y = (float)h.y; fI[j] = v;
        }
        // sum_r V[r].x == 13 * X0 exactly (cos columns sum to 0) -> no reduce
        float invt = 0.5f / (13.0f * fR[0].x);

#pragma unroll
        for (int rr = 0; rr < 4; rr++) {
            int r = q + (rr << 2);
            if (r < HALFV) {
                v2f acc = fR[0];
                int a = 0;
#pragma unroll
                for (int j = 1; j < 7; j++) {
                    a += r; if (a >= HALFV) a -= HALFV;   // a = (j*r)%13
                    acc += fR[j] * c2tab[a] - fI[j] * s2tab[a];
                }
                int c0 = (14 * r) % MODV;
                int c1 = c0 + 13; if (c1 >= MODV) c1 -= MODV;
                obuf[ir * MODV + c0] = __logf((acc.x + acc.y) * invt + 1e-12f);
                obuf[ir * MODV + c1] = __logf((acc.x - acc.y) * invt + 1e-12f);
            }
        }
    }
    __syncthreads();

    // cooperative coalesced store of the 64x26 fp32 block (1664 floats)
    {
        float* o = out + (size_t)b * (NV * MODV);
        int t = threadIdx.x;
#pragma unroll
        for (int k = 0; k < 6; k++)
            o[t + k * 256] = obuf[t + k * 256];
        int idx = t + 1536;
        if (idx < NV * MODV) o[idx] = obuf[idx];
    }
}

extern "C" void kernel_launch(void* const* d_in, const int* in_sizes, int n_in,
                              void* d_out, int out_size, void* d_ws, size_t ws_size,
                              hipStream_t stream)
{
    const int*   P  = (const int*)d_in[0];      // (1024, 64) int32
    const float* kp = (const float*)d_in[1];    // (4096, 26) fp32
    float* out = (float*)d_out;                 // log_probs ++ key_probs
    float* key_probs_out = out + (size_t)BV * NV * MODV;
    uint* ws = (uint*)d_ws;                     // 5,537,792 B used

    hipLaunchKernelGGL(prep_kernel, dim3(64, 7), dim3(256), 0, stream,
                       kp, key_probs_out, ws);
    hipLaunchKernelGGL(chain_kernel, dim3(BV), dim3(256), 0, stream,
                       P, ws, out);
}

// Round 4
// 78.470 us; speedup vs baseline: 1.0008x; 1.0008x over previous
//
#include <hip/hip_runtime.h>
#include <hip/hip_fp16.h>

#define MODV 26
#define HALFV 13
#define NV 64
#define BV 1024

typedef float v2f __attribute__((ext_vector_type(2)));
typedef _Float16 h2 __attribute__((ext_vector_type(2)));

// ---------------------------------------------------------------------------
// Spectral representation. For each (l,p,i):
//   Kp[c] = sum_{k: p*k%26==c} softmax(key_param[l,i,:])[k]
// CRT split (Z26 = Z2 x Z13): S[r] = Kp[even]+Kp[odd], D[r] = Kp[even]-Kp[odd]
// 13-pt DFT: X_j = sum_r x[r] e^{-2pi i jr/13}, j=0..6 (X_0 real).
// Chain = 63 pointwise complex products + ONE inverse DFT at the end.
// Entry = 13 packed-fp16 words: w[0..6]=(S_re,D_re) j=0..6, w[7..12]=(S_im,D_im).
//
// R6: word-group-major 4096-B entry layout -> every VMEM instruction
//     unit-stride coalesced; entry uint-offset = (l*26+p)<<10.
//     [0,256) uint4 {w0..w3} lane i at i*4; [256,512) {w4..w7};
//     [512,768) {w8..w11}; [768,832) w12; rest pad.
// R9: R6 base (4096 stride + single rolling prefetch, both measured-good)
//     + parallel 4x fp32 epilogue (4 threads/row; normalizer needs no
//     reduction: sum_r V[r].x == 13 * X0 exactly, cos columns sum to 0).
//     R7's 3328 stride + depth-2 prefetch reverted (measured +0.8 us net).
// ---------------------------------------------------------------------------

__device__ __forceinline__ h2 bch2(uint u) { return __builtin_bit_cast(h2, u); }
__device__ __forceinline__ uint bcu(h2 v) { return __builtin_bit_cast(uint, v); }

__device__ __forceinline__ uint packw(v2f v)
{
    uint hs = (uint)__half_as_ushort(__float2half_rn(v.x));
    uint hd = (uint)__half_as_ushort(__float2half_rn(v.y));
    return hs | (hd << 16);
}

// state (RE[0..6], IM[1..6]) *= spectrum in packed words w13[0..12]
__device__ __forceinline__ void mulspec_w(h2* __restrict__ RE,
                                          h2* __restrict__ IM,
                                          const uint* __restrict__ w13)
{
    RE[0] *= bch2(w13[0]);
#pragma unroll
    for (int j = 1; j < 7; j++) {
        h2 kr = bch2(w13[j]), ki = bch2(w13[6 + j]);
        h2 nre = RE[j] * kr - IM[j] * ki;
        h2 nim = RE[j] * ki + IM[j] * kr;
        RE[j] = nre; IM[j] = nim;
    }
}

// ---------------------------------------------------------------------------
// Kernel 1: grid (64 l-slabs x 7 p-groups) x 256. Wave w handles
// p = 4*blockIdx.y + w (skip p>=26); one statically-unrolled p-block per
// wave (wave-uniform branch -> compile-time scatter indices).
// ---------------------------------------------------------------------------
__global__ __launch_bounds__(256)
void prep_kernel(const float* __restrict__ key_param,
                 float* __restrict__ key_probs_out,
                 uint* __restrict__ ws)
{
    __shared__ float slab[NV * MODV];   // 6656 B
    int l = blockIdx.x;
    int t = threadIdx.x;
    int i = t & 63;
    int w = t >> 6;
    int p = (blockIdx.y << 2) + w;

#pragma unroll
    for (int j = 0; j < 7; j++) {
        int idx = t + j * 256;
        if (idx < NV * MODV) slab[idx] = key_param[l * NV * MODV + idx];
    }
    __syncthreads();

    float x[MODV];
    float m = -1e30f;
#pragma unroll
    for (int k = 0; k < MODV; k++) {
        x[k] = slab[i * MODV + k];
        m = fmaxf(m, x[k]);
    }
    float s = 0.f;
#pragma unroll
    for (int k = 0; k < MODV; k++) { x[k] = __expf(x[k] - m); s += x[k]; }
    float inv = 1.f / s;
#pragma unroll
    for (int k = 0; k < MODV; k++) x[k] *= inv;

    if (blockIdx.y == 0 && w == 0) {
#pragma unroll
        for (int k = 0; k < MODV; k++)
            key_probs_out[((l << 6) + i) * MODV + k] = x[k];
    }
    if (p >= MODV) return;

    float c13[HALFV], s13[HALFV];
#pragma unroll
    for (int k = 0; k < HALFV; k++) {
        float a = 0.4833219467f * (float)k;    // 2*pi/13
        __sincosf(a, &s13[k], &c13[k]);
    }

#pragma unroll
    for (int pc = 0; pc < MODV; pc++) {
        if (pc != p) continue;          // wave-uniform; one block executes

        float Kp[MODV];
#pragma unroll
        for (int c = 0; c < MODV; c++) Kp[c] = 0.f;
#pragma unroll
        for (int k = 0; k < MODV; k++) Kp[(pc * k) % MODV] += x[k];  // static

        v2f V[HALFV];                    // (S[r], D[r])
#pragma unroll
        for (int r = 0; r < HALFV; r++) {
            int c0 = (14 * r) % MODV;
            int c1 = (13 + 14 * r) % MODV;
            v2f v; v.x = Kp[c0] + Kp[c1]; v.y = Kp[c0] - Kp[c1];
            V[r] = v;
        }

        uint hw[HALFV];
        {   // j = 0 (DC, real)
            v2f acc = V[0];
#pragma unroll
            for (int r = 1; r < HALFV; r++) acc += V[r];
            hw[0] = packw(acc);
        }
#pragma unroll
        for (int j = 1; j < 7; j++) {
            v2f re = V[0];
            v2f im; im.x = 0.f; im.y = 0.f;
#pragma unroll
            for (int r = 1; r < HALFV; r++) {
                int a = (j * r) % HALFV;            // compile-time
                re += V[r] * c13[a];
                im -= V[r] * s13[a];
            }
            hw[j]     = packw(re);
            hw[6 + j] = packw(im);
        }
        // transposed entry: all four stores below are unit-stride coalesced
        uint* dst = ws + ((size_t)(l * MODV + pc) << 10);
        *(uint4*)(dst + (i << 2))         = make_uint4(hw[0], hw[1], hw[2],  hw[3]);
        *(uint4*)(dst + 256 + (i << 2))   = make_uint4(hw[4], hw[5], hw[6],  hw[7]);
        *(uint4*)(dst + 512 + (i << 2))   = make_uint4(hw[8], hw[9], hw[10], hw[11]);
        dst[768 + i] = hw[12];
    }
}

// ---------------------------------------------------------------------------
// Kernel 2: one block (4 waves) per b. Wave w pointwise-multiplies the 16
// spectra for l in [16w,16w+16) in packed fp16 (rolling prefetch), LDS tree
// combine, then the fp32 inverse DFT + log epilogue parallelized over all
// 256 threads (4 threads per row), and the 64x26 block stored coalesced.
// ---------------------------------------------------------------------------
__global__ __launch_bounds__(256, 4)
void chain_kernel(const int* __restrict__ P,
                  const uint* __restrict__ ws,
                  float* __restrict__ out)
{
    __shared__ int Pl[NV];
    __shared__ uint sbuf[2][64][HALFV];  // 6656 B
    __shared__ float obuf[NV * MODV];    // 6656 B, epilogue staging
    __shared__ float c2tab[HALFV], s2tab[HALFV];  // 2*cos, 2*sin tables

    int b = blockIdx.x;
    int w = threadIdx.x >> 6;
    int i = threadIdx.x & 63;
    if (threadIdx.x < NV) Pl[threadIdx.x] = P[(b << 6) + threadIdx.x];
    if (threadIdx.x < HALFV) {
        float a = 0.4833219467f * (float)threadIdx.x;   // 2*pi/13
        float sv, cv;
        __sincosf(a, &sv, &cv);
        c2tab[threadIdx.x] = 2.f * cv;
        s2tab[threadIdx.x] = 2.f * sv;
    }
    __syncthreads();

    int base = w << 4;
    int i4 = i << 2;                     // uint offset of lane's uint4

    h2 RE[7], IM[7];                     // IM[0] unused
    {
        const uint* e = ws + ((size_t)(base * MODV + Pl[base]) << 10);
        uint4 a  = *(const uint4*)(e + i4);
        uint4 bq = *(const uint4*)(e + 256 + i4);
        uint4 cq = *(const uint4*)(e + 512 + i4);
        uint w12 = e[768 + i];
        uint wd[HALFV] = {a.x, a.y, a.z, a.w, bq.x, bq.y, bq.z, bq.w,
                          cq.x, cq.y, cq.z, cq.w, w12};
#pragma unroll
        for (int j = 0; j < 7; j++) RE[j] = bch2(wd[j]);
#pragma unroll
        for (int j = 1; j < 7; j++) IM[j] = bch2(wd[6 + j]);
    }

    uint4 n0, n1, n2; uint n12;
    {
        int l = base + 1;
        const uint* e = ws + ((size_t)(l * MODV + Pl[l]) << 10);
        n0 = *(const uint4*)(e + i4);      n1 = *(const uint4*)(e + 256 + i4);
        n2 = *(const uint4*)(e + 512 + i4); n12 = e[768 + i];
    }

#pragma unroll 1
    for (int s = 1; s < 16; s++) {
        uint cw[HALFV] = {n0.x, n0.y, n0.z, n0.w, n1.x, n1.y, n1.z, n1.w,
                          n2.x, n2.y, n2.z, n2.w, n12};
        if (s < 15) {
            int l = base + s + 1;
            const uint* e = ws + ((size_t)(l * MODV + Pl[l]) << 10);
            n0 = *(const uint4*)(e + i4);      n1 = *(const uint4*)(e + 256 + i4);
            n2 = *(const uint4*)(e + 512 + i4); n12 = e[768 + i];
        }
        mulspec_w(RE, IM, cw);
    }

    // tree combine: (w0 <- w1), (w2 <- w3), then w0 <- w2 (packed words)
    if (w == 1 || w == 3) {
        int buf = w >> 1;
#pragma unroll
        for (int j = 0; j < 7; j++) sbuf[buf][i][j] = bcu(RE[j]);
#pragma unroll
        for (int j = 1; j < 7; j++) sbuf[buf][i][6 + j] = bcu(IM[j]);
    }
    __syncthreads();
    if (w == 0) {
        uint K[HALFV];
#pragma unroll
        for (int r = 0; r < HALFV; r++) K[r] = sbuf[0][i][r];
        mulspec_w(RE, IM, K);
    } else if (w == 2) {
        uint K[HALFV];
#pragma unroll
        for (int r = 0; r < HALFV; r++) K[r] = sbuf[1][i][r];
        mulspec_w(RE, IM, K);
#pragma unroll
        for (int j = 0; j < 7; j++) sbuf[1][i][j] = bcu(RE[j]);
#pragma unroll
        for (int j = 1; j < 7; j++) sbuf[1][i][6 + j] = bcu(IM[j]);
    }
    __syncthreads();
    if (w == 0) {
        uint K[HALFV];
#pragma unroll
        for (int r = 0; r < HALFV; r++) K[r] = sbuf[1][i][r];
        mulspec_w(RE, IM, K);
        // publish final spectrum for the parallel epilogue
#pragma unroll
        for (int j = 0; j < 7; j++) sbuf[0][i][j] = bcu(RE[j]);
#pragma unroll
        for (int j = 1; j < 7; j++) sbuf[0][i][6 + j] = bcu(IM[j]);
    }
    __syncthreads();

    // ---- parallel fp32 epilogue: 4 threads per row, r in {q,q+4,q+8(,12)}
    {
        int ir = threadIdx.x >> 2;      // row 0..63
        int q  = threadIdx.x & 3;

        uint wrow[HALFV];
#pragma unroll
        for (int j = 0; j < HALFV; j++) wrow[j] = sbuf[0][ir][j];

        v2f fR[7], fI[7];
#pragma unroll
        for (int j = 0; j < 7; j++) {
            h2 h = bch2(wrow[j]);
            v2f v; v.x = (float)h.x; v.y = (float)h.y; fR[j] = v;
        }
#pragma unroll
        for (int j = 1; j < 7; j++) {
            h2 h = bch2(wrow[6 + j]);
            v2f v; v.x = (float)h.x; v.y = (float)h.y; fI[j] = v;
        }
        // sum_r V[r].x == 13 * X0 exactly (cos columns sum to 0) -> no reduce
        float invt = 0.5f / (13.0f * fR[0].x);

#pragma unroll
        for (int rr = 0; rr < 4; rr++) {
            int r = q + (rr << 2);
            if (r < HALFV) {
                v2f acc = fR[0];
                int a = 0;
#pragma unroll
                for (int j = 1; j < 7; j++) {
                    a += r; if (a >= HALFV) a -= HALFV;   // a = (j*r)%13
                    acc += fR[j] * c2tab[a] - fI[j] * s2tab[a];
                }
                int c0 = (14 * r) % MODV;
                int c1 = c0 + 13; if (c1 >= MODV) c1 -= MODV;
                obuf[ir * MODV + c0] = __logf((acc.x + acc.y) * invt + 1e-12f);
                obuf[ir * MODV + c1] = __logf((acc.x - acc.y) * invt + 1e-12f);
            }
        }
    }
    __syncthreads();

    // cooperative coalesced store of the 64x26 fp32 block (1664 floats)
    {
        float* o = out + (size_t)b * (NV * MODV);
        int t = threadIdx.x;
#pragma unroll
        for (int k = 0; k < 6; k++)
            o[t + k * 256] = obuf[t + k * 256];
        int idx = t + 1536;
        if (idx < NV * MODV) o[idx] = obuf[idx];
    }
}

extern "C" void kernel_launch(void* const* d_in, const int* in_sizes, int n_in,
                              void* d_out, int out_size, void* d_ws, size_t ws_size,
                              hipStream_t stream)
{
    const int*   P  = (const int*)d_in[0];      // (1024, 64) int32
    const float* kp = (const float*)d_in[1];    // (4096, 26) fp32
    float* out = (float*)d_out;                 // log_probs ++ key_probs
    float* key_probs_out = out + (size_t)BV * NV * MODV;
    uint* ws = (uint*)d_ws;                     // 6,815,744 B used

    hipLaunchKernelGGL(prep_kernel, dim3(64, 7), dim3(256), 0, stream,
                       kp, key_probs_out, ws);
    hipLaunchKernelGGL(chain_kernel, dim3(BV), dim3(256), 0, stream,
                       P, ws, out);
}